// Round 1
// baseline (506.617 us; speedup 1.0000x reference)
//
#include <hip/hip_runtime.h>
#include <math.h>

#define TOPK   4
#define NBINS  33          // MAX_NUM_BINS + 1
#define CPA    132         // corners per anchor = 4*33
#define STATD  20
#define HID    64
#define NCLS   80
#define APB    64          // anchors per block
#define BS     256
#define HSTR   68          // s_h row stride in floats (64 + 4 pad, keeps 16B align)

// Fused: softmax+top4 -> stat -> MLP(20->64->1) -> scores + q, one block = 64 anchors
__global__ __launch_bounds__(BS, 4) void lqe_fused(
    const float* __restrict__ scores,
    const float* __restrict__ corners,
    const float* __restrict__ W1,    // (20,64) row-major
    const float* __restrict__ b1,    // (64)
    const float* __restrict__ W2,    // (64,1)
    const float* __restrict__ b2,    // (1)
    float* __restrict__ out)
{
    // s_buf: corners during phase 1a, then h[64][HSTR] during phase 1b/reduce
    __shared__ float s_buf[APB * CPA];        // 33792 B  (>= 64*68*4 = 17408 B)
    __shared__ float s_stat[APB * STATD];     //  5120 B
    __shared__ float s_q[APB];                //   256 B

    const int tid  = threadIdx.x;
    const int lane = tid & 63;
    const long long aBase = (long long)blockIdx.x * APB;

    // ---- stage corners (coalesced float4): 2112 vec4, 8.25/thread ----
    {
        const float4* src = (const float4*)(corners + aBase * CPA);
        float4* dst = (float4*)s_buf;
        for (int i = tid; i < (APB * CPA) / 4; i += BS) dst[i] = src[i];
    }
    __syncthreads();

    // ---- phase 1a: softmax + top-4, thread = (anchor, side) ----
    {
        const int a    = tid >> 2;
        const int side = tid & 3;
        const float* pc = s_buf + a * CPA + side * NBINS;  // 33*tid: conflict-free

        float p[NBINS];
        #pragma unroll
        for (int k = 0; k < NBINS; ++k) p[k] = pc[k];

        float m = p[0];
        #pragma unroll
        for (int k = 1; k < NBINS; ++k) m = fmaxf(m, p[k]);

        float s = 0.0f;
        #pragma unroll
        for (int k = 0; k < NBINS; ++k) { p[k] = __expf(p[k] - m); s += p[k]; }

        // top-4 via branchless insertion network (exps > 0, so -1 is safe init)
        float t0 = -1.0f, t1 = -1.0f, t2 = -1.0f, t3 = -1.0f;
        #pragma unroll
        for (int k = 0; k < NBINS; ++k) {
            const float v  = p[k];
            const float b0 = fmaxf(t0, v),  c0 = fminf(t0, v);
            const float b1_ = fmaxf(t1, c0), c1 = fminf(t1, c0);
            const float b2_ = fmaxf(t2, c1), c2 = fminf(t2, c1);
            const float b3 = fmaxf(t3, c2);
            t0 = b0; t1 = b1_; t2 = b2_; t3 = b3;
        }

        const float inv = 1.0f / s;
        t0 *= inv; t1 *= inv; t2 *= inv; t3 *= inv;
        const float mean = (t0 + t1 + t2 + t3) * 0.25f;

        float* st = s_stat + a * STATD + side * (TOPK + 1);    // 5*tid: conflict-free
        st[0] = t0; st[1] = t1; st[2] = t2; st[3] = t3; st[4] = mean;
    }
    __syncthreads();   // s_stat ready; s_buf (corners) dead -> reusable as s_h

    // ---- prefetch scores into registers (hides 167.8 MB read under the MLP) ----
    float4 r0, r1, r2, r3, r4;
    {
        const float4* sc = (const float4*)(scores + aBase * NCLS);
        r0 = sc[tid        ];
        r1 = sc[tid + 1*BS ];
        r2 = sc[tid + 2*BS ];
        r3 = sc[tid + 3*BS ];
        r4 = sc[tid + 4*BS ];
    }

    // ---- weights (loaded AFTER phase 1a: shorter live range, L2-hot) ----
    float w1c[STATD];
    #pragma unroll
    for (int d = 0; d < STATD; ++d) w1c[d] = W1[d * HID + lane];
    const float bias = b1[lane];
    const float w2v  = W2[lane];
    const float b2v  = b2[0];

    // ---- phase 1b: MLP; wave handles 16 anchors, lane = hidden unit ----
    // h value goes to LDS transpose buffer instead of 6-deep shfl reduce
    float* s_h = s_buf;   // [APB][HSTR]
    {
        const int wave = tid >> 6;
        #pragma unroll
        for (int i = 0; i < APB / 4; ++i) {
            const int a = wave * (APB / 4) + i;
            const float4* sp = (const float4*)(s_stat + a * STATD);
            const float4 s0 = sp[0], s1 = sp[1], s2 = sp[2], s3 = sp[3], s4 = sp[4];
            float acc = bias;
            acc = fmaf(s0.x, w1c[0],  acc); acc = fmaf(s0.y, w1c[1],  acc);
            acc = fmaf(s0.z, w1c[2],  acc); acc = fmaf(s0.w, w1c[3],  acc);
            acc = fmaf(s1.x, w1c[4],  acc); acc = fmaf(s1.y, w1c[5],  acc);
            acc = fmaf(s1.z, w1c[6],  acc); acc = fmaf(s1.w, w1c[7],  acc);
            acc = fmaf(s2.x, w1c[8],  acc); acc = fmaf(s2.y, w1c[9],  acc);
            acc = fmaf(s2.z, w1c[10], acc); acc = fmaf(s2.w, w1c[11], acc);
            acc = fmaf(s3.x, w1c[12], acc); acc = fmaf(s3.y, w1c[13], acc);
            acc = fmaf(s3.z, w1c[14], acc); acc = fmaf(s3.w, w1c[15], acc);
            acc = fmaf(s4.x, w1c[16], acc); acc = fmaf(s4.y, w1c[17], acc);
            acc = fmaf(s4.z, w1c[18], acc); acc = fmaf(s4.w, w1c[19], acc);
            // bank = (68a + lane) % 32 = (4a + lane) % 32 -> 2 lanes/bank: free
            s_h[a * HSTR + lane] = fmaxf(acc, 0.0f) * w2v;
        }
    }
    __syncthreads();

    // ---- reduce: 4 threads per anchor, 16 values each, then 2 shfls ----
    {
        const int a  = tid >> 2;
        const int qd = tid & 3;
        const float4* hp = (const float4*)(s_h + a * HSTR + qd * 16);
        const float4 h0 = hp[0], h1 = hp[1], h2 = hp[2], h3 = hp[3];
        float v = ((h0.x + h0.y) + (h0.z + h0.w))
                + ((h1.x + h1.y) + (h1.z + h1.w))
                + ((h2.x + h2.y) + (h2.z + h2.w))
                + ((h3.x + h3.y) + (h3.z + h3.w));
        v += __shfl_xor(v, 1, 64);
        v += __shfl_xor(v, 2, 64);
        if (qd == 0) s_q[a] = v + b2v;
    }
    __syncthreads();

    // ---- streaming add + store (scores already in registers) ----
    {
        float4* op = (float4*)(out + aBase * NCLS);
        const float q0 = s_q[(tid         ) / (NCLS / 4)];
        const float q1 = s_q[(tid + 1*BS  ) / (NCLS / 4)];
        const float q2 = s_q[(tid + 2*BS  ) / (NCLS / 4)];
        const float q3 = s_q[(tid + 3*BS  ) / (NCLS / 4)];
        const float q4 = s_q[(tid + 4*BS  ) / (NCLS / 4)];
        r0.x += q0; r0.y += q0; r0.z += q0; r0.w += q0;
        r1.x += q1; r1.y += q1; r1.z += q1; r1.w += q1;
        r2.x += q2; r2.y += q2; r2.z += q2; r2.w += q2;
        r3.x += q3; r3.y += q3; r3.z += q3; r3.w += q3;
        r4.x += q4; r4.y += q4; r4.z += q4; r4.w += q4;
        op[tid        ] = r0;
        op[tid + 1*BS ] = r1;
        op[tid + 2*BS ] = r2;
        op[tid + 3*BS ] = r3;
        op[tid + 4*BS ] = r4;
    }
}

extern "C" void kernel_launch(void* const* d_in, const int* in_sizes, int n_in,
                              void* d_out, int out_size, void* d_ws, size_t ws_size,
                              hipStream_t stream) {
    const float* scores  = (const float*)d_in[0];
    const float* corners = (const float*)d_in[1];
    const float* W1      = (const float*)d_in[2];
    const float* b1      = (const float*)d_in[3];
    const float* W2      = (const float*)d_in[4];
    const float* b2      = (const float*)d_in[5];
    float* out = (float*)d_out;
    (void)d_ws; (void)ws_size;

    const int nAnchors = in_sizes[0] / NCLS;          // 524288
    const int blocks   = nAnchors / APB;              // 8192 (exact)

    lqe_fused<<<blocks, BS, 0, stream>>>(scores, corners, W1, b1, W2, b2, out);
}